// Round 4
// baseline (531.129 us; speedup 1.0000x reference)
//
#include <hip/hip_runtime.h>
#include <math.h>

#define B_   16
#define C_   256
#define N_   16384
#define K_   64
#define CO_  512

typedef __attribute__((ext_vector_type(8))) short short8;
typedef __attribute__((ext_vector_type(4))) short short4v;
typedef __attribute__((ext_vector_type(4))) float floatx4;

__device__ inline unsigned int f2bf(float f) {
    unsigned int u = __float_as_uint(f);
    return (u + 0x7FFFu + ((u >> 16) & 1u)) >> 16;   // RNE (inputs finite)
}

// XOR-swizzled [row][64col] bf16 LDS tile: conflict-free writes (n-pairs across
// lanes) and conflict-free b128 reads (8 consecutive cols per lane).
// phys_sh(row,col) = row*64 + (((col>>2) ^ (row&14))<<2) + (col&3)

// ---------------------------------------------------------------------------
// K1: fused l2norm -> logits(MFMA) -> softmax -> aggregation(MFMA)
// 512 blocks (2/CU), 512 threads, 8 chunks of 64 columns, register-prefetch
// software pipeline. waves_per_eu(4,4) pins 4 waves/EU -> 128-VGPR budget so
// the 32-reg prefetch survives in registers (round-3 spilled at 64 VGPRs).
// LDS 79,872 B -> 2 blocks/CU.
// ---------------------------------------------------------------------------
__global__ __attribute__((amdgpu_flat_work_group_size(512, 512),
                          amdgpu_waves_per_eu(4, 4)))
void k1_assign_agg(
    const float* __restrict__ x, const float* __restrict__ aw,
    const float* __restrict__ ab, float* __restrict__ agg,
    float* __restrict__ asum)
{
    __shared__ __align__(16) unsigned char smem[79872];
    unsigned short* x_cn = (unsigned short*)smem;              // [256][64] swizzled, 32768
    unsigned short* x_nc = (unsigned short*)(smem + 32768);    // [64][260], 33280
    unsigned short* a_ld = (unsigned short*)(smem + 66048);    // [64][64] swizzled, 8192
    float* colsq = (float*)(smem + 74240);                     // [64][17], 4352
    float* rnorm = (float*)(smem + 78592);                     // [64], 256
    float* part  = (float*)(smem + 78848);                     // [64][4], 1024
    float* red   = part;                                       // [8][16] epilogue overlay

    const int t    = threadIdx.x;
    const int lane = t & 63;
    const int wav  = t >> 6;
    const int b    = blockIdx.x >> 5;
    const int tile = blockIdx.x & 31;
    const float* xb = x + (size_t)b * ((size_t)C_ * N_) + tile * 512;

    const int j16 = lane & 15;
    const int g4  = lane >> 4;         // 0..3
    const int mw  = wav & 3;           // phase A: k-tile
    const int jw  = wav >> 2;          // phase A: j-half
    const int p   = t & 31;            // staging: n-pair
    const int g   = t >> 5;            // staging: c-group (0..15)

    // hoisted w A-fragments + bias
    short8 wf[8];
    {
        const float* wrow = aw + (mw * 16 + j16) * 256 + g4 * 8;
        #pragma unroll
        for (int ki = 0; ki < 8; ++ki) {
            const float* q = wrow + ki * 32;
            short8 f;
            #pragma unroll
            for (int i = 0; i < 8; ++i) f[i] = (short)f2bf(q[i]);
            wf[ki] = f;
        }
    }
    const float4 abf = *(const float4*)(ab + mw * 16 + g4 * 4);

    floatx4 acc[4][2];
    #pragma unroll
    for (int m = 0; m < 4; ++m)
        #pragma unroll
        for (int c2 = 0; c2 < 2; ++c2)
            acc[m][c2] = (floatx4){0.f, 0.f, 0.f, 0.f};
    float asr[4] = {0.f, 0.f, 0.f, 0.f};

    // ---- prologue: prefetch chunk 0 into registers ----
    float2 v[16];
    {
        const float* ps = xb + 2 * p;
        #pragma unroll
        for (int i = 0; i < 16; ++i)
            v[i] = *(const float2*)(ps + (size_t)(g * 16 + i) * N_);
    }

    for (int chunk = 0; chunk < 8; ++chunk) {
        __syncthreads();                               // B0: prev chunk's LDS consumed
        // ---- stage prefetched regs -> LDS (both layouts) + col sumsq ----
        float sq0 = 0.f, sq1 = 0.f;
        #pragma unroll
        for (int half = 0; half < 2; ++half) {
            unsigned int hL[8], hH[8];
            #pragma unroll
            for (int i = 0; i < 8; ++i) {
                float2 vv = v[half * 8 + i];
                sq0 += vv.x * vv.x; sq1 += vv.y * vv.y;
                hL[i] = f2bf(vv.x); hH[i] = f2bf(vv.y);
                int c = g * 16 + half * 8 + i;
                ((unsigned int*)x_cn)[c * 32 + (((p >> 1) ^ (c & 14)) << 1) + (p & 1)]
                    = hL[i] | (hH[i] << 16);
            }
            unsigned short* r0 = x_nc + (2 * p) * 260 + g * 16 + half * 8;
            unsigned short* r1 = r0 + 260;
            uint2 wl0, wl1, wh0, wh1;
            wl0.x = hL[0] | (hL[1] << 16); wl0.y = hL[2] | (hL[3] << 16);
            wl1.x = hL[4] | (hL[5] << 16); wl1.y = hL[6] | (hL[7] << 16);
            wh0.x = hH[0] | (hH[1] << 16); wh0.y = hH[2] | (hH[3] << 16);
            wh1.x = hH[4] | (hH[5] << 16); wh1.y = hH[6] | (hH[7] << 16);
            *(uint2*)(r0 + 0) = wl0; *(uint2*)(r0 + 4) = wl1;
            *(uint2*)(r1 + 0) = wh0; *(uint2*)(r1 + 4) = wh1;
        }
        colsq[(2 * p) * 17 + g]     = sq0;
        colsq[(2 * p + 1) * 17 + g] = sq1;
        // ---- issue next chunk's global loads (stay in flight across barriers) ----
        if (chunk < 7) {
            const float* ps = xb + (chunk + 1) * 64 + 2 * p;
            #pragma unroll
            for (int i = 0; i < 16; ++i)
                v[i] = *(const float2*)(ps + (size_t)(g * 16 + i) * N_);
        }
        __syncthreads();                               // B1
        if (t < 64) {
            float s = 0.f;
            #pragma unroll
            for (int q = 0; q < 16; ++q) s += colsq[t * 17 + q];
            rnorm[t] = 1.0f / fmaxf(sqrtf(s), 1e-12f);
        }
        __syncthreads();                               // B2
        // ---- phase A: logits = w . xn (MFMA over c) ----
        floatx4 ct0 = {0.f, 0.f, 0.f, 0.f}, ct1 = {0.f, 0.f, 0.f, 0.f};
        {
            const unsigned short* rA0 = x_nc + (jw * 32 + j16) * 260 + g4 * 8;
            const unsigned short* rA1 = rA0 + 16 * 260;
            #pragma unroll
            for (int ki = 0; ki < 8; ++ki) {
                short4v a0 = *(const short4v*)(rA0 + ki * 32);
                short4v a1 = *(const short4v*)(rA0 + ki * 32 + 4);
                short4v b0 = *(const short4v*)(rA1 + ki * 32);
                short4v b1 = *(const short4v*)(rA1 + ki * 32 + 4);
                short8 f0, f1;
                #pragma unroll
                for (int i = 0; i < 4; ++i) {
                    f0[i] = a0[i]; f0[i + 4] = a1[i];
                    f1[i] = b0[i]; f1[i + 4] = b1[i];
                }
                ct0 = __builtin_amdgcn_mfma_f32_16x16x32_bf16(wf[ki], f0, ct0, 0, 0, 0);
                ct1 = __builtin_amdgcn_mfma_f32_16x16x32_bf16(wf[ki], f1, ct1, 0, 0, 0);
            }
        }
        // ---- softmax over k=64 ----
        const float rn0 = rnorm[jw * 32 + j16];
        const float rn1 = rnorm[jw * 32 + 16 + j16];
        float e0[4], e1[4];
        float p0 = 0.f, p1 = 0.f;
        #pragma unroll
        for (int r = 0; r < 4; ++r) {
            float l0 = ct0[r] * rn0 + ((const float*)&abf)[r];
            float l1 = ct1[r] * rn1 + ((const float*)&abf)[r];
            e0[r] = __expf(l0); e1[r] = __expf(l1);
            p0 += e0[r]; p1 += e1[r];
        }
        p0 += __shfl_xor(p0, 16); p0 += __shfl_xor(p0, 32);
        p1 += __shfl_xor(p1, 16); p1 += __shfl_xor(p1, 32);
        if (lane < 16) {
            part[(jw * 32 + j16) * 4 + mw]      = p0;
            part[(jw * 32 + 16 + j16) * 4 + mw] = p1;
        }
        __syncthreads();                               // B3
        {
            float4 q0 = *(const float4*)(part + (jw * 32 + j16) * 4);
            float4 q1 = *(const float4*)(part + (jw * 32 + 16 + j16) * 4);
            float i0 = 1.0f / (q0.x + q0.y + q0.z + q0.w);
            float i1 = 1.0f / (q1.x + q1.y + q1.z + q1.w);
            float s0 = rn0 * i0, s1 = rn1 * i1;
            const int n0c = jw * 32 + j16, n1c = n0c + 16;
            #pragma unroll
            for (int r = 0; r < 4; ++r) {
                int k = mw * 16 + g4 * 4 + r;
                a_ld[k * 64 + ((((n0c) >> 2) ^ (k & 14)) << 2) + (n0c & 3)]
                    = (unsigned short)f2bf(e0[r] * s0);
                a_ld[k * 64 + ((((n1c) >> 2) ^ (k & 14)) << 2) + (n1c & 3)]
                    = (unsigned short)f2bf(e1[r] * s1);
                asr[r] += e0[r] * i0 + e1[r] * i1;
            }
        }
        __syncthreads();                               // B4
        // ---- phase B: agg += a' . xn^T (MFMA over n) ----
        {
            const int cb = wav * 32;
            #pragma unroll
            for (int ki = 0; ki < 2; ++ki) {
                const int sub = ki * 8 + g4 * 2;       // even
                short8 af[4];
                #pragma unroll
                for (int m = 0; m < 4; ++m) {
                    int k = m * 16 + j16;
                    af[m] = *(const short8*)&a_ld[k * 64 + ((sub ^ (k & 14)) << 2)];
                }
                #pragma unroll
                for (int c2 = 0; c2 < 2; ++c2) {
                    int c = cb + c2 * 16 + j16;
                    short8 bfv = *(const short8*)&x_cn[c * 64 + ((sub ^ (c & 14)) << 2)];
                    #pragma unroll
                    for (int m = 0; m < 4; ++m)
                        acc[m][c2] = __builtin_amdgcn_mfma_f32_16x16x32_bf16(af[m], bfv, acc[m][c2], 0, 0, 0);
                }
            }
        }
    }

    // ---- epilogue: asum reduce + one atomic flush of agg ----
    __syncthreads();
    #pragma unroll
    for (int r = 0; r < 4; ++r) {
        asr[r] += __shfl_xor(asr[r], 1);
        asr[r] += __shfl_xor(asr[r], 2);
        asr[r] += __shfl_xor(asr[r], 4);
        asr[r] += __shfl_xor(asr[r], 8);
    }
    if (j16 == 0) {
        #pragma unroll
        for (int r = 0; r < 4; ++r) red[wav * 16 + g4 * 4 + r] = asr[r];
    }
    __syncthreads();
    if (t < 64) {
        float s = red[(t >> 4) * 16 + (t & 15)] + red[((t >> 4) + 4) * 16 + (t & 15)];
        atomicAdd(&asum[b * 64 + t], s);
    }
    #pragma unroll
    for (int m = 0; m < 4; ++m)
        #pragma unroll
        for (int c2 = 0; c2 < 2; ++c2)
            #pragma unroll
            for (int r = 0; r < 4; ++r) {
                int k = m * 16 + g4 * 4 + r;
                int c = wav * 32 + c2 * 16 + j16;
                atomicAdd(&agg[((size_t)(b * 64 + k)) * 256 + c], acc[m][c2][r]);
            }
}

// ---------------------------------------------------------------------------
// K2a: vlad = agg - asum*cent, intra-norm over C, accumulate global norm.
// ---------------------------------------------------------------------------
__global__ void k2a_vlad_norm(const float* __restrict__ agg,
                              const float* __restrict__ asum,
                              const float* __restrict__ cent,
                              float* __restrict__ vn,
                              float* __restrict__ gsq)
{
    const int b = blockIdx.x >> 6;
    const int k = blockIdx.x & 63;
    const int lane = threadIdx.x;
    const float as = asum[b * 64 + k];
    float v[4];
    float sq = 0.f;
    #pragma unroll
    for (int i = 0; i < 4; ++i) {
        int c = lane + 64 * i;
        v[i] = agg[((size_t)(b * 64 + k)) * 256 + c] - as * cent[k * 256 + c];
        sq += v[i] * v[i];
    }
    #pragma unroll
    for (int off = 32; off >= 1; off >>= 1) sq += __shfl_xor(sq, off);
    float scale = 1.0f / fmaxf(sqrtf(sq), 1e-12f);
    #pragma unroll
    for (int i = 0; i < 4; ++i) {
        int c = lane + 64 * i;
        vn[(size_t)b * 16384 + k * 256 + c] = v[i] * scale;
    }
    if (lane == 0) atomicAdd(&gsq[b], sq * scale * scale);
}

// ---------------------------------------------------------------------------
// K2b: y[b,co] (+)= vn[b,:] . red_w[co,:]  (fp32, LDS-staged vn for reuse)
// Grid: 256 blocks = 64 co-octets x 4 K-quarters; 256 thr = 8 co x 32 lanes.
// vn traffic: 256 KB/block = 64 MB total (was 512 MB); rw read exactly once.
// ---------------------------------------------------------------------------
__global__ __launch_bounds__(256) void k2b_gemm(
    const float* __restrict__ vn, const float* __restrict__ rw,
    float* __restrict__ y)
{
    __shared__ float vns[16][1032];          // 66 KB, padded row
    const int t   = threadIdx.x;
    const int cg  = t >> 5;                  // 0..7 co sub
    const int tk  = t & 31;                  // k lane
    const int cog = blockIdx.x >> 2;
    const int kq  = blockIdx.x & 3;
    const int co  = cog * 8 + cg;
    const float4* vn4 = (const float4*)vn;
    const float4* rw4 = (const float4*)rw;

    float acc[16];
    #pragma unroll
    for (int bb = 0; bb < 16; ++bb) acc[bb] = 0.f;

    for (int ch = 0; ch < 4; ++ch) {
        const int kc4 = kq * 1024 + ch * 256;        // float4 index base
        __syncthreads();
        #pragma unroll
        for (int bb = 0; bb < 16; ++bb) {
            float4 vv = vn4[(size_t)bb * 4096 + kc4 + t];
            *(float4*)&vns[bb][t << 2] = vv;
        }
        __syncthreads();
        const float4* rwr = rw4 + (size_t)co * 4096 + kc4;
        #pragma unroll
        for (int j = 0; j < 8; ++j) {
            float4 w = rwr[tk + 32 * j];
            #pragma unroll
            for (int bb = 0; bb < 16; ++bb) {
                float4 vv = *(const float4*)&vns[bb][(tk + 32 * j) << 2];
                acc[bb] += w.x * vv.x + w.y * vv.y + w.z * vv.z + w.w * vv.w;
            }
        }
    }
    // reduce over 32 k-lanes (xor<32 stays within half-wave = one co)
    #pragma unroll
    for (int off = 16; off >= 1; off >>= 1)
        #pragma unroll
        for (int bb = 0; bb < 16; ++bb)
            acc[bb] += __shfl_xor(acc[bb], off);
    if (tk == 0) {
        #pragma unroll
        for (int bb = 0; bb < 16; ++bb)
            atomicAdd(&y[bb * 512 + co], acc[bb]);
    }
}

// ---------------------------------------------------------------------------
// K2c: y = s/gnorm + rb, then BatchNorm1d (batch stats) + ReLU.
// ---------------------------------------------------------------------------
__global__ void k2c_bn(const float* __restrict__ y,
                       const float* __restrict__ gsq,
                       const float* __restrict__ rb,
                       const float* __restrict__ bnw,
                       const float* __restrict__ bnb,
                       float* __restrict__ out)
{
    const int co = threadIdx.x;
    const float rbv = rb[co];
    float vals[16];
    float m = 0.f;
    #pragma unroll
    for (int bb = 0; bb < 16; ++bb) {
        float gv = fmaxf(sqrtf(gsq[bb]), 1e-12f);
        vals[bb] = y[bb * 512 + co] / gv + rbv;
        m += vals[bb];
    }
    m *= (1.0f / 16.0f);
    float var = 0.f;
    #pragma unroll
    for (int bb = 0; bb < 16; ++bb) {
        float d = vals[bb] - m;
        var += d * d;
    }
    var *= (1.0f / 16.0f);
    float inv = 1.0f / sqrtf(var + 1e-5f);
    float w = bnw[co], bias = bnb[co];
    #pragma unroll
    for (int bb = 0; bb < 16; ++bb) {
        float o = w * (vals[bb] - m) * inv + bias;
        out[bb * 512 + co] = fmaxf(o, 0.f);
    }
}

// ---------------------------------------------------------------------------
extern "C" void kernel_launch(void* const* d_in, const int* in_sizes, int n_in,
                              void* d_out, int out_size, void* d_ws, size_t ws_size,
                              hipStream_t stream)
{
    const float* x    = (const float*)d_in[0];
    const float* aw   = (const float*)d_in[1];
    const float* ab   = (const float*)d_in[2];
    const float* cent = (const float*)d_in[3];
    const float* rw   = (const float*)d_in[4];
    const float* rb   = (const float*)d_in[5];
    const float* bnw  = (const float*)d_in[6];
    const float* bnb  = (const float*)d_in[7];
    float* out = (float*)d_out;

    char* ws = (char*)d_ws;
    float* agg  = (float*)(ws);                    // [0, 1 MB)
    float* asum = (float*)(ws + 0x100000);         // 4 KB
    float* gsq  = (float*)(ws + 0x101000);         // 64 B (padded)
    float* y    = (float*)(ws + 0x102000);         // 32 KB
    float* vn   = (float*)(ws + 0x110000);         // 1 MB

    hipMemsetAsync(ws, 0, 0x10A000, stream);       // zero agg+asum+gsq+y

    hipLaunchKernelGGL(k1_assign_agg, dim3(512), dim3(512), 0, stream,
                       x, aw, ab, agg, asum);
    hipLaunchKernelGGL(k2a_vlad_norm, dim3(B_ * K_), dim3(64), 0, stream,
                       agg, asum, cent, vn, gsq);
    hipLaunchKernelGGL(k2b_gemm, dim3(256), dim3(256), 0, stream,
                       vn, rw, y);
    hipLaunchKernelGGL(k2c_bn, dim3(1), dim3(512), 0, stream,
                       y, gsq, rb, bnw, bnb, out);
}